// Round 1
// baseline (6832.481 us; speedup 1.0000x reference)
//
#include <hip/hip_runtime.h>
#include <math.h>

#define NPTS 16384
#define NB 8
#define NS 2048
#define DZ 256

typedef float v2f __attribute__((ext_vector_type(2)));

// ---------------- ws layout (float offsets) ----------------
#define OFF_SCAL 0                           // [0]=sum_vel [1]=sum_reg [2..25]=ot[3][8]
#define OFF_LU   64
#define OFF_LV   (OFF_LU + NB*NS)
#define OFF_F    (OFF_LV + NB*NS)
#define OFF_G    (OFF_F + 3*NB*NS)
#define ZERO_FLOATS (OFF_G + 3*NB*NS)        // everything below here is zero-initialized
#define OFF_IDX  ZERO_FLOATS                 // int[8][2048]
#define OFF_YP   (OFF_IDX + NB*NS)           // float4[8][2048]
#define OFF_TP   (OFF_YP + NB*NS*4)          // float4[2048]
#define OFF_XP   (OFF_TP + NS*4)             // float4[8][2048]
#define OFF_PERM (OFF_XP + NB*NS*4)          // float[8][2048][3]
#define OFF_Z    (OFF_PERM + NB*NS*3)        // float[8][256]
#define OFF_HB   (OFF_Z + NB*DZ)             // float[8][256]
// total = OFF_HB + NB*DZ = 340032 floats = 1.36 MB

// ============================================================
// Farthest point sampling: one block per batch, sequential 2048
// iterations, registers hold 16 pts/thread as float2 SoA.
// Exact-match arithmetic (no FMA contraction) + first-index
// argmax tie-break to track jnp reference bit-for-bit.
// ============================================================
__global__ __launch_bounds__(1024) void fps_kernel(const float* __restrict__ x,
                                                   int* __restrict__ sel){
  #pragma clang fp contract(off)
  const int b = blockIdx.x, tid = threadIdx.x;
  const float* xb = x + (size_t)b * NPTS * 3;
  float c[48];
  {
    const float4* s4 = (const float4*)(xb + (size_t)tid * 48);
    #pragma unroll
    for (int q = 0; q < 12; q++){
      float4 v = s4[q];
      c[4*q] = v.x; c[4*q+1] = v.y; c[4*q+2] = v.z; c[4*q+3] = v.w;
    }
  }
  v2f X[8], Y[8], Z[8], D[8];
  #pragma unroll
  for (int j = 0; j < 8; j++){
    v2f vx = {c[6*j],   c[6*j+3]};
    v2f vy = {c[6*j+1], c[6*j+4]};
    v2f vz = {c[6*j+2], c[6*j+5]};
    v2f vi = {INFINITY, INFINITY};
    X[j] = vx; Y[j] = vy; Z[j] = vz; D[j] = vi;
  }
  __shared__ float sC[3];
  __shared__ int sIdx;
  __shared__ unsigned long long sKey;
  if (tid == 0){ sIdx = 0; sKey = ~0ull; sC[0] = c[0]; sC[1] = c[1]; sC[2] = c[2]; }
  __syncthreads();

  for (int i = 0; i < NS; i++){
    const float c0 = sC[0], c1 = sC[1], c2 = sC[2];
    if (tid == 0) sel[b*NS + i] = sIdx;
    v2f c0v = {c0, c0}, c1v = {c1, c1}, c2v = {c2, c2};
    v2f lm = {-INFINITY, -INFINITY};
    #pragma unroll
    for (int j = 0; j < 8; j++){
      v2f dx = X[j] - c0v;
      v2f dy = Y[j] - c1v;
      v2f dz = Z[j] - c2v;
      v2f d2 = (dx*dx + dy*dy) + dz*dz;   // contract(off): matches XLA mul/add
      v2f nd = __builtin_elementwise_min(D[j], d2);
      D[j] = nd;
      lm = __builtin_elementwise_max(lm, nd);
    }
    const float lmaxT = fmaxf(lm.x, lm.y);
    float wmax = lmaxT;
    #pragma unroll
    for (int o = 32; o; o >>= 1) wmax = fmaxf(wmax, __shfl_xor(wmax, o, 64));
    if (lmaxT == wmax){
      // this thread holds (one of) the wave maxima: find first k, race via u64 key
      int kk = 15;
      #pragma unroll
      for (int j = 7; j >= 0; j--){
        if (D[j].y == lmaxT) kk = 2*j + 1;
        if (D[j].x == lmaxT) kk = 2*j;
      }
      unsigned long long key =
        ((unsigned long long)(~__float_as_uint(lmaxT)) << 32) |
        (unsigned int)(tid*16 + kk);
      atomicMin(&sKey, key);
    }
    __syncthreads();
    const unsigned long long k2 = sKey;
    const int gidx = (int)(k2 & 0xffffffffu);
    if (tid == (gidx >> 4)){
      const int kk = gidx & 15;
      float px = 0.f, py = 0.f, pz = 0.f;
      #pragma unroll
      for (int j = 0; j < 8; j++){
        if (kk == 2*j)   { px = X[j].x; py = Y[j].x; pz = Z[j].x; }
        if (kk == 2*j+1) { px = X[j].y; py = Y[j].y; pz = Z[j].y; }
      }
      sC[0] = px; sC[1] = py; sC[2] = pz;
      sIdx = gidx;
      sKey = ~0ull;
    }
    __syncthreads();
  }
}

// ============================================================
// Gather selected points, pack as {x,y,z,|p|^2}
// ============================================================
__global__ __launch_bounds__(256) void gather_pack_kernel(const float* __restrict__ x,
                                                          const int* __restrict__ sel,
                                                          float4* __restrict__ yp){
  const int b = blockIdx.y;
  const int k = blockIdx.x*256 + threadIdx.x;
  const int p = sel[b*NS + k];
  const float* s = x + ((size_t)b*NPTS + p)*3;
  const float x0 = s[0], x1 = s[1], x2 = s[2];
  const float sq = fmaf(x0,x0, fmaf(x1,x1, x2*x2));
  yp[b*NS + k] = make_float4(x0, x1, x2, sq);
}

__global__ __launch_bounds__(256) void pack_t_kernel(const float* __restrict__ tmpl,
                                                     float4* __restrict__ tp,
                                                     float* __restrict__ sumreg){
  __shared__ float sbuf[4];
  const int k = blockIdx.x*256 + threadIdx.x;
  const float x0 = tmpl[3*k], x1 = tmpl[3*k+1], x2 = tmpl[3*k+2];
  const float sq = fmaf(x0,x0, fmaf(x1,x1, x2*x2));
  tp[k] = make_float4(x0, x1, x2, sq);
  const float n = sqrtf(sq) - 1.0f;
  float v = n*n;
  #pragma unroll
  for (int o = 32; o; o >>= 1) v += __shfl_xor(v, o, 64);
  if ((threadIdx.x & 63) == 0) sbuf[threadIdx.x >> 6] = v;
  __syncthreads();
  if (threadIdx.x == 0){
    float t = 0.f;
    for (int w = 0; w < 4; w++) t += sbuf[w];
    atomicAdd(sumreg, t);
  }
}

// z[b,c] = max_n relu(y @ W_enc + b_enc)
__global__ __launch_bounds__(256) void feat_z_kernel(const float4* __restrict__ yp,
                                                     const float* __restrict__ Wenc,
                                                     const float* __restrict__ benc,
                                                     float* __restrict__ z){
  __shared__ float4 sy[NS];
  const int b = blockIdx.x, tid = threadIdx.x;
  for (int j = tid; j < NS; j += 256) sy[j] = yp[b*NS + j];
  __syncthreads();
  const float w0 = Wenc[tid], w1 = Wenc[256+tid], w2 = Wenc[512+tid], bb = benc[tid];
  float m = -INFINITY;
  for (int n = 0; n < NS; n++){
    float4 q = sy[n];
    float v = fmaf(q.x, w0, fmaf(q.y, w1, fmaf(q.z, w2, bb)));
    m = fmaxf(m, fmaxf(v, 0.0f));
  }
  z[b*DZ + tid] = m;
}

// h_base[b,c] = b1[c] + t*W1[3,c] + sum_k z[b,k]*W1[4+k,c]
__global__ __launch_bounds__(256) void hbase_kernel(const float* __restrict__ z,
                                                    const float* __restrict__ W1,
                                                    const float* __restrict__ b1,
                                                    const float* __restrict__ tarr,
                                                    float* __restrict__ hb){
  __shared__ float sz[DZ];
  const int b = blockIdx.x, cidx = threadIdx.x;
  sz[cidx] = z[b*DZ + cidx];
  __syncthreads();
  const float t = fminf(fmaxf(tarr[b], 1e-5f), (float)(1.0 - 1e-5));
  float acc = fmaf(t, W1[3*256 + cidx], b1[cidx]);
  for (int k = 0; k < DZ; k++) acc = fmaf(sz[k], W1[(4 + k)*256 + cidx], acc);
  hb[b*DZ + cidx] = acc;
}

// ============================================================
// Generic sinkhorn half-iteration: out_i = oScale*LSE_j(val_ij)
// val_ij = (dual_j*dMul + dAdd - H*sqJ) + (-H*sqI) + twoH*dot(pi,pj)
// Cost matrix recomputed on the fly; J-set staged in LDS as
// float4{x,y,z,E}. 1024 thr = 16 waves = 16 output rows/block.
// ============================================================
__device__ __forceinline__ void sink_pass_core(const float4* __restrict__ PI, long piStride,
                                               const float4* __restrict__ PJ, long pjStride,
                                               const float* __restrict__ dIn,
                                               float* __restrict__ dOut,
                                               float H, float twoH, float dMul, float dAdd,
                                               float oScale, float4* S){
  const int tid = threadIdx.x;
  const int b = blockIdx.z;
  {
    const float4* pj = PJ + pjStride*b;
    const float* din = dIn + (size_t)b*NS;
    for (int j = tid; j < NS; j += 1024){
      float4 q = pj[j];
      float E = fmaf(-H, q.w, fmaf(din[j], dMul, dAdd));
      S[j] = make_float4(q.x, q.y, q.z, E);
    }
  }
  __syncthreads();
  const int w = tid >> 6, lane = tid & 63;
  const int i = blockIdx.x*16 + w;
  const float4 pi = PI[piStride*b + i];
  const float R = -H*pi.w;
  float mx = -INFINITY, s = 0.0f;
  #pragma unroll 2
  for (int k = 0; k < 8; k++){
    const int j0 = k*256 + lane;
    float4 a0 = S[j0], a1 = S[j0+64], a2 = S[j0+128], a3 = S[j0+192];
    float v0 = fmaf(twoH, fmaf(pi.x,a0.x, fmaf(pi.y,a0.y, pi.z*a0.z)), a0.w + R);
    float v1 = fmaf(twoH, fmaf(pi.x,a1.x, fmaf(pi.y,a1.y, pi.z*a1.z)), a1.w + R);
    float v2 = fmaf(twoH, fmaf(pi.x,a2.x, fmaf(pi.y,a2.y, pi.z*a2.z)), a2.w + R);
    float v3 = fmaf(twoH, fmaf(pi.x,a3.x, fmaf(pi.y,a3.y, pi.z*a3.z)), a3.w + R);
    float m4 = fmaxf(fmaxf(v0, v1), fmaxf(v2, v3));
    float nm = fmaxf(mx, m4);
    s = fmaf(s, __expf(mx - nm),
             __expf(v0 - nm) + __expf(v1 - nm) + __expf(v2 - nm) + __expf(v3 - nm));
    mx = nm;
  }
  #pragma unroll
  for (int o = 32; o; o >>= 1){
    float om = __shfl_xor(mx, o, 64);
    float os = __shfl_xor(s,  o, 64);
    float nm = fmaxf(mx, om);
    s = fmaf(s, __expf(mx - nm), os*__expf(om - nm));
    mx = nm;
  }
  if (lane == 0) dOut[(size_t)b*NS + i] = oScale*(mx + __logf(s));
}

__global__ __launch_bounds__(1024) void sink_assign_kernel(const float4* __restrict__ tp,
                                                           const float4* __restrict__ yp,
                                                           float* __restrict__ lu,
                                                           float* __restrict__ lv,
                                                           int dir, float H, float twoH){
  __shared__ float4 S[NS];
  if (dir == 0) sink_pass_core(tp, 0,  yp, NS, lv, lu, H, twoH, 1.0f, 0.0f, -1.0f, S);
  else          sink_pass_core(yp, NS, tp, 0,  lu, lv, H, twoH, 1.0f, 0.0f, -1.0f, S);
}

// 3 OT problems fused along gridDim.y: p0=(x1,y) p1=(x1,x1) p2=(y,y)
__global__ __launch_bounds__(1024) void sink_ot_kernel(const float4* __restrict__ xp,
                                                       const float4* __restrict__ yp,
                                                       float* __restrict__ F,
                                                       float* __restrict__ G,
                                                       int dir, float H, float twoH,
                                                       float dMul, float dAdd, float oScale){
  __shared__ float4 S[NS];
  const int p = blockIdx.y;
  const float4* first  = (p == 2) ? yp : xp;
  const float4* second = (p == 1) ? xp : yp;
  float* f = F + (size_t)p*NB*NS;
  float* g = G + (size_t)p*NB*NS;
  if (dir == 0) sink_pass_core(first,  NS, second, NS, g, f, H, twoH, dMul, dAdd, oScale, S);
  else          sink_pass_core(second, NS, first,  NS, f, g, H, twoH, dMul, dAdd, oScale, S);
}

// target_perm[b,n,:] = sum_m exp(logK + lu_n + lv_m) * y_m
__global__ __launch_bounds__(1024) void perm_kernel(const float4* __restrict__ tp,
                                                    const float4* __restrict__ yp,
                                                    const float* __restrict__ lu,
                                                    const float* __restrict__ lv,
                                                    float* __restrict__ perm,
                                                    float H, float twoH){
  __shared__ float4 S[NS];
  const int tid = threadIdx.x, b = blockIdx.z;
  for (int j = tid; j < NS; j += 1024){
    float4 q = yp[(size_t)b*NS + j];
    float E = fmaf(-H, q.w, lv[(size_t)b*NS + j]);
    S[j] = make_float4(q.x, q.y, q.z, E);
  }
  __syncthreads();
  const int w = tid >> 6, lane = tid & 63;
  const int i = blockIdx.x*16 + w;
  const float4 pi = tp[i];
  const float R = fmaf(-H, pi.w, lu[(size_t)b*NS + i]);
  float a0 = 0.f, a1 = 0.f, a2 = 0.f;
  #pragma unroll 2
  for (int k = 0; k < 8; k++){
    #pragma unroll
    for (int u = 0; u < 4; u++){
      const int j = k*256 + u*64 + lane;
      float4 q = S[j];
      float val = fmaf(twoH, fmaf(pi.x,q.x, fmaf(pi.y,q.y, pi.z*q.z)), q.w + R);
      float wgt = __expf(val);
      a0 = fmaf(wgt, q.x, a0);
      a1 = fmaf(wgt, q.y, a1);
      a2 = fmaf(wgt, q.z, a2);
    }
  }
  #pragma unroll
  for (int o = 32; o; o >>= 1){
    a0 += __shfl_xor(a0, o, 64);
    a1 += __shfl_xor(a1, o, 64);
    a2 += __shfl_xor(a2, o, 64);
  }
  if (lane == 0){
    float* d = perm + ((size_t)b*NS + i)*3;
    d[0] = a0; d[1] = a1; d[2] = a2;
  }
}

// v_pred MLP (z-part prefolded into hb), loss_velocity partial, x1 pack
__global__ __launch_bounds__(128) void mlp_kernel(const float4* __restrict__ tp,
                                                  const float* __restrict__ perm,
                                                  const float* __restrict__ hb,
                                                  const float* __restrict__ W1,
                                                  const float* __restrict__ W2,
                                                  const float* __restrict__ b2,
                                                  const float* __restrict__ tarr,
                                                  float4* __restrict__ xp,
                                                  float* __restrict__ sumvel){
  __shared__ float sw0[256], sw1[256], sw2[256], shb[256], sW2[768];
  __shared__ float sred[2];
  const int tid = threadIdx.x;
  const int r = blockIdx.x*128 + tid;          // global row, batch-uniform per block
  const int b = r >> 11, n = r & (NS - 1);
  for (int k = tid; k < 256; k += 128){
    sw0[k] = W1[k]; sw1[k] = W1[256+k]; sw2[k] = W1[512+k]; shb[k] = hb[b*256 + k];
  }
  for (int k = tid; k < 768; k += 128) sW2[k] = W2[k];
  __syncthreads();
  const float t = fminf(fmaxf(tarr[b], 1e-5f), (float)(1.0 - 1e-5));
  const float4 T = tp[n];
  const float pm0 = perm[(size_t)r*3], pm1 = perm[(size_t)r*3+1], pm2 = perm[(size_t)r*3+2];
  const float omt = 1.0f - t;
  const float xt0 = omt*T.x + t*pm0;
  const float xt1 = omt*T.y + t*pm1;
  const float xt2 = omt*T.z + t*pm2;
  float a0 = b2[0], a1 = b2[1], a2 = b2[2];
  for (int cc = 0; cc < 256; cc++){
    float pre = fmaf(xt0, sw0[cc], fmaf(xt1, sw1[cc], fmaf(xt2, sw2[cc], shb[cc])));
    float h = fmaxf(pre, 0.0f);
    a0 = fmaf(h, sW2[3*cc],   a0);
    a1 = fmaf(h, sW2[3*cc+1], a1);
    a2 = fmaf(h, sW2[3*cc+2], a2);
  }
  const float vg0 = pm0 - T.x, vg1 = pm1 - T.y, vg2 = pm2 - T.z;
  const float d0 = a0 - vg0, d1 = a1 - vg1, d2 = a2 - vg2;
  float ls = fmaf(d0,d0, fmaf(d1,d1, d2*d2));
  const float x0 = T.x + a0, x1 = T.y + a1, x2 = T.z + a2;
  const float sq = fmaf(x0,x0, fmaf(x1,x1, x2*x2));
  xp[r] = make_float4(x0, x1, x2, sq);
  #pragma unroll
  for (int o = 32; o; o >>= 1) ls += __shfl_xor(ls, o, 64);
  if ((tid & 63) == 0) sred[tid >> 6] = ls;
  __syncthreads();
  if (tid == 0) atomicAdd(sumvel, sred[0] + sred[1]);
}

__global__ __launch_bounds__(256) void ot_sum_kernel(const float* __restrict__ F,
                                                     const float* __restrict__ G,
                                                     float* __restrict__ ot){
  __shared__ float sbuf[8];
  const int pb = blockIdx.x;                    // p*8 + b
  const float* f = F + (size_t)pb*NS;
  const float* g = G + (size_t)pb*NS;
  float sf = 0.f, sg = 0.f;
  for (int j = threadIdx.x; j < NS; j += 256){ sf += f[j]; sg += g[j]; }
  #pragma unroll
  for (int o = 32; o; o >>= 1){ sf += __shfl_xor(sf, o, 64); sg += __shfl_xor(sg, o, 64); }
  if ((threadIdx.x & 63) == 0){ sbuf[threadIdx.x >> 6] = sf; sbuf[4 + (threadIdx.x >> 6)] = sg; }
  __syncthreads();
  if (threadIdx.x == 0){
    float tf = 0.f, tg = 0.f;
    for (int w = 0; w < 4; w++){ tf += sbuf[w]; tg += sbuf[4 + w]; }
    ot[pb] = tf/(float)NS + tg/(float)NS;
  }
}

__global__ void finalize_kernel(const float* __restrict__ scal, float* __restrict__ out){
  if (threadIdx.x == 0){
    const float* ot = scal + 2;
    float lot = 0.f;
    for (int b = 0; b < NB; b++)
      lot += ot[0*NB + b] - 0.5f*ot[1*NB + b] - 0.5f*ot[2*NB + b];
    lot /= (float)NB;
    const float lvv = scal[0] / (float)(NB*NS*3);
    const float lrg = scal[1] / (float)NS;
    out[0] = lvv + 0.1f*lot + 0.01f*lrg;
    out[1] = lvv;
    out[2] = lot;
    out[3] = lrg;
  }
}

extern "C" void kernel_launch(void* const* d_in, const int* in_sizes, int n_in,
                              void* d_out, int out_size, void* d_ws, size_t ws_size,
                              hipStream_t stream){
  (void)in_sizes; (void)n_in; (void)out_size; (void)ws_size;
  const float* target = (const float*)d_in[0];
  const float* tarr   = (const float*)d_in[1];
  const float* tmpl   = (const float*)d_in[2];
  const float* Wenc   = (const float*)d_in[3];
  const float* benc   = (const float*)d_in[4];
  const float* W1     = (const float*)d_in[5];
  const float* b1     = (const float*)d_in[6];
  const float* W2     = (const float*)d_in[7];
  const float* b2     = (const float*)d_in[8];
  float* out = (float*)d_out;
  float* ws  = (float*)d_ws;

  float*  scal = ws + OFF_SCAL;
  float*  lu   = ws + OFF_LU;
  float*  lv   = ws + OFF_LV;
  float*  F    = ws + OFF_F;
  float*  G    = ws + OFF_G;
  int*    sel  = (int*)(ws + OFF_IDX);
  float4* yp   = (float4*)(ws + OFF_YP);
  float4* tp   = (float4*)(ws + OFF_TP);
  float4* xp   = (float4*)(ws + OFF_XP);
  float*  perm = ws + OFF_PERM;
  float*  z    = ws + OFF_Z;
  float*  hb   = ws + OFF_HB;

  hipMemsetAsync(ws, 0, (size_t)ZERO_FLOATS*sizeof(float), stream);

  fps_kernel<<<NB, 1024, 0, stream>>>(target, sel);
  gather_pack_kernel<<<dim3(8, NB), 256, 0, stream>>>(target, sel, yp);
  pack_t_kernel<<<8, 256, 0, stream>>>(tmpl, tp, scal + 1);
  feat_z_kernel<<<NB, 256, 0, stream>>>(yp, Wenc, benc, z);
  hbase_kernel<<<NB, 256, 0, stream>>>(z, W1, b1, tarr, hb);

  const float INVREG = 1.0f/0.05f;
  for (int it = 0; it < 20; ++it){
    sink_assign_kernel<<<dim3(128,1,NB), 1024, 0, stream>>>(tp, yp, lu, lv, 0, INVREG, 2.0f*INVREG);
    sink_assign_kernel<<<dim3(128,1,NB), 1024, 0, stream>>>(tp, yp, lu, lv, 1, INVREG, 2.0f*INVREG);
  }
  perm_kernel<<<dim3(128,1,NB), 1024, 0, stream>>>(tp, yp, lu, lv, perm, INVREG, 2.0f*INVREG);
  mlp_kernel<<<128, 128, 0, stream>>>(tp, perm, hb, W1, W2, b2, tarr, xp, scal + 0);

  const float EPS    = (float)(0.05*0.05);
  const float INVEPS = 1.0f/EPS;
  const float HOT    = 0.5f*INVEPS;
  const float LOGNU  = (float)(-log(2048.0));
  for (int it = 0; it < 20; ++it){
    sink_ot_kernel<<<dim3(128,3,NB), 1024, 0, stream>>>(xp, yp, F, G, 0, HOT, INVEPS, INVEPS, LOGNU, -EPS);
    sink_ot_kernel<<<dim3(128,3,NB), 1024, 0, stream>>>(xp, yp, F, G, 1, HOT, INVEPS, INVEPS, LOGNU, -EPS);
  }
  ot_sum_kernel<<<24, 256, 0, stream>>>(F, G, scal + 2);
  finalize_kernel<<<1, 64, 0, stream>>>(scal, out);
}

// Round 2
// 5747.836 us; speedup vs baseline: 1.1887x; 1.1887x over previous
//
#include <hip/hip_runtime.h>
#include <math.h>

#define NPTS 16384
#define NB 8
#define NS 2048
#define DZ 256

typedef float v2f __attribute__((ext_vector_type(2)));

// ---------------- ws layout (float offsets) ----------------
#define OFF_SCAL 0                           // [0]=sum_vel [1]=sum_reg [2..25]=ot[3][8]
#define OFF_LU   64
#define OFF_LV   (OFF_LU + NB*NS)
#define OFF_F    (OFF_LV + NB*NS)
#define OFF_G    (OFF_F + 3*NB*NS)
#define ZERO_FLOATS (OFF_G + 3*NB*NS)        // everything below here is zero-initialized
#define OFF_IDX  ZERO_FLOATS                 // int[8][2048]
#define OFF_YP   (OFF_IDX + NB*NS)           // float4[8][2048]
#define OFF_TP   (OFF_YP + NB*NS*4)          // float4[2048]
#define OFF_XP   (OFF_TP + NS*4)             // float4[8][2048]
#define OFF_PERM (OFF_XP + NB*NS*4)          // float[8][2048][3]
#define OFF_Z    (OFF_PERM + NB*NS*3)        // float[8][256]
#define OFF_HB   (OFF_Z + NB*DZ)             // float[8][256]

// ============================================================
// Farthest point sampling, v2: 512 threads, 32 pts/thread (v2f),
// ONE barrier per iteration.
//  - per-thread argmax: tree max + backward first-index scan
//    (bit-identical to verified R1 logic, contract(off))
//  - per-wave: u64 key = (~valbits<<32)|gidx, 6-level min
//    butterfly -> wave-uniform, lane0 writes slot
//  - slots double-buffered on iteration parity -> no 2nd barrier
//  - block winner: every thread min-scans 8 slot keys; centroid
//    coords re-fetched from global (same-address broadcast, L2-hot)
// ============================================================
__global__ __launch_bounds__(512) void fps_kernel(const float* __restrict__ x,
                                                  int* __restrict__ sel){
  #pragma clang fp contract(off)
  const int b = blockIdx.x, tid = threadIdx.x;
  const float* xb = x + (size_t)b * NPTS * 3;
  float c[96];
  {
    const float4* s4 = (const float4*)(xb + (size_t)tid * 96);
    #pragma unroll
    for (int q = 0; q < 24; q++){
      float4 v = s4[q];
      c[4*q] = v.x; c[4*q+1] = v.y; c[4*q+2] = v.z; c[4*q+3] = v.w;
    }
  }
  v2f X[16], Y[16], Z[16], D[16];
  #pragma unroll
  for (int j = 0; j < 16; j++){
    X[j] = (v2f){c[6*j],   c[6*j+3]};
    Y[j] = (v2f){c[6*j+1], c[6*j+4]};
    Z[j] = (v2f){c[6*j+2], c[6*j+5]};
    D[j] = (v2f){INFINITY, INFINITY};
  }
  __shared__ unsigned long long sK[2][8];
  // initial centroid = point 0 (farthest=0)
  float c0 = xb[0], c1 = xb[1], c2 = xb[2];
  int widx = 0;
  const int wv = tid >> 6, lane = tid & 63;

  for (int i = 0; i < NS; i++){
    if (tid == 0) sel[b*NS + i] = widx;
    const v2f c0v = {c0,c0}, c1v = {c1,c1}, c2v = {c2,c2};
    #pragma unroll
    for (int j = 0; j < 16; j++){
      v2f dx = X[j] - c0v;
      v2f dy = Y[j] - c1v;
      v2f dz = Z[j] - c2v;
      v2f d2 = (dx*dx + dy*dy) + dz*dz;   // contract(off): matches np sub/mul/add
      D[j] = __builtin_elementwise_min(D[j], d2);
    }
    // tree max over the 16 v2f
    v2f m0 = __builtin_elementwise_max(D[0],  D[1]);
    v2f m1 = __builtin_elementwise_max(D[2],  D[3]);
    v2f m2 = __builtin_elementwise_max(D[4],  D[5]);
    v2f m3 = __builtin_elementwise_max(D[6],  D[7]);
    v2f m4 = __builtin_elementwise_max(D[8],  D[9]);
    v2f m5 = __builtin_elementwise_max(D[10], D[11]);
    v2f m6 = __builtin_elementwise_max(D[12], D[13]);
    v2f m7 = __builtin_elementwise_max(D[14], D[15]);
    m0 = __builtin_elementwise_max(m0, m1);
    m2 = __builtin_elementwise_max(m2, m3);
    m4 = __builtin_elementwise_max(m4, m5);
    m6 = __builtin_elementwise_max(m6, m7);
    m0 = __builtin_elementwise_max(m0, m2);
    m4 = __builtin_elementwise_max(m4, m6);
    m0 = __builtin_elementwise_max(m0, m4);
    const float lmax = fmaxf(m0.x, m0.y);
    // first-index scan (verified R1 logic)
    int kk = 31;
    #pragma unroll
    for (int j = 15; j >= 0; j--){
      if (D[j].y == lmax) kk = 2*j + 1;
      if (D[j].x == lmax) kk = 2*j;
    }
    unsigned long long key =
      ((unsigned long long)(~__float_as_uint(lmax)) << 32) |
      (unsigned int)(tid*32 + kk);
    // wave min-butterfly on u64 key
    #pragma unroll
    for (int o = 32; o; o >>= 1){
      unsigned long long ok = __shfl_xor(key, o, 64);
      key = (ok < key) ? ok : key;
    }
    const int par = i & 1;
    if (lane == 0) sK[par][wv] = key;
    __syncthreads();
    unsigned long long best = sK[par][0];
    #pragma unroll
    for (int w = 1; w < 8; w++){
      unsigned long long k2 = sK[par][w];
      best = (k2 < best) ? k2 : best;
    }
    widx = (int)(best & 0xffffffffu);
    const float* cp = xb + (size_t)widx * 3;
    c0 = cp[0]; c1 = cp[1]; c2 = cp[2];
  }
}

// ============================================================
// Gather selected points, pack as {x,y,z,|p|^2}
// ============================================================
__global__ __launch_bounds__(256) void gather_pack_kernel(const float* __restrict__ x,
                                                          const int* __restrict__ sel,
                                                          float4* __restrict__ yp){
  const int b = blockIdx.y;
  const int k = blockIdx.x*256 + threadIdx.x;
  const int p = sel[b*NS + k];
  const float* s = x + ((size_t)b*NPTS + p)*3;
  const float x0 = s[0], x1 = s[1], x2 = s[2];
  const float sq = fmaf(x0,x0, fmaf(x1,x1, x2*x2));
  yp[b*NS + k] = make_float4(x0, x1, x2, sq);
}

__global__ __launch_bounds__(256) void pack_t_kernel(const float* __restrict__ tmpl,
                                                     float4* __restrict__ tp,
                                                     float* __restrict__ sumreg){
  __shared__ float sbuf[4];
  const int k = blockIdx.x*256 + threadIdx.x;
  const float x0 = tmpl[3*k], x1 = tmpl[3*k+1], x2 = tmpl[3*k+2];
  const float sq = fmaf(x0,x0, fmaf(x1,x1, x2*x2));
  tp[k] = make_float4(x0, x1, x2, sq);
  const float n = sqrtf(sq) - 1.0f;
  float v = n*n;
  #pragma unroll
  for (int o = 32; o; o >>= 1) v += __shfl_xor(v, o, 64);
  if ((threadIdx.x & 63) == 0) sbuf[threadIdx.x >> 6] = v;
  __syncthreads();
  if (threadIdx.x == 0){
    float t = 0.f;
    for (int w = 0; w < 4; w++) t += sbuf[w];
    atomicAdd(sumreg, t);
  }
}

// z[b,c] = max_n relu(y @ W_enc + b_enc)
__global__ __launch_bounds__(256) void feat_z_kernel(const float4* __restrict__ yp,
                                                     const float* __restrict__ Wenc,
                                                     const float* __restrict__ benc,
                                                     float* __restrict__ z){
  __shared__ float4 sy[NS];
  const int b = blockIdx.x, tid = threadIdx.x;
  for (int j = tid; j < NS; j += 256) sy[j] = yp[b*NS + j];
  __syncthreads();
  const float w0 = Wenc[tid], w1 = Wenc[256+tid], w2 = Wenc[512+tid], bb = benc[tid];
  float m = -INFINITY;
  for (int n = 0; n < NS; n++){
    float4 q = sy[n];
    float v = fmaf(q.x, w0, fmaf(q.y, w1, fmaf(q.z, w2, bb)));
    m = fmaxf(m, fmaxf(v, 0.0f));
  }
  z[b*DZ + tid] = m;
}

// h_base[b,c] = b1[c] + t*W1[3,c] + sum_k z[b,k]*W1[4+k,c]
__global__ __launch_bounds__(256) void hbase_kernel(const float* __restrict__ z,
                                                    const float* __restrict__ W1,
                                                    const float* __restrict__ b1,
                                                    const float* __restrict__ tarr,
                                                    float* __restrict__ hb){
  __shared__ float sz[DZ];
  const int b = blockIdx.x, cidx = threadIdx.x;
  sz[cidx] = z[b*DZ + cidx];
  __syncthreads();
  const float t = fminf(fmaxf(tarr[b], 1e-5f), (float)(1.0 - 1e-5));
  float acc = fmaf(t, W1[3*256 + cidx], b1[cidx]);
  for (int k = 0; k < DZ; k++) acc = fmaf(sz[k], W1[(4 + k)*256 + cidx], acc);
  hb[b*DZ + cidx] = acc;
}

// ============================================================
// Generic sinkhorn half-iteration: out_i = oScale*LSE_j(val_ij)
// val_ij = (dual_j*dMul + dAdd - H*sqJ) + (-H*sqI) + twoH*dot(pi,pj)
// ============================================================
__device__ __forceinline__ void sink_pass_core(const float4* __restrict__ PI, long piStride,
                                               const float4* __restrict__ PJ, long pjStride,
                                               const float* __restrict__ dIn,
                                               float* __restrict__ dOut,
                                               float H, float twoH, float dMul, float dAdd,
                                               float oScale, float4* S){
  const int tid = threadIdx.x;
  const int b = blockIdx.z;
  {
    const float4* pj = PJ + pjStride*b;
    const float* din = dIn + (size_t)b*NS;
    for (int j = tid; j < NS; j += 1024){
      float4 q = pj[j];
      float E = fmaf(-H, q.w, fmaf(din[j], dMul, dAdd));
      S[j] = make_float4(q.x, q.y, q.z, E);
    }
  }
  __syncthreads();
  const int w = tid >> 6, lane = tid & 63;
  const int i = blockIdx.x*16 + w;
  const float4 pi = PI[piStride*b + i];
  const float R = -H*pi.w;
  float mx = -INFINITY, s = 0.0f;
  #pragma unroll 2
  for (int k = 0; k < 8; k++){
    const int j0 = k*256 + lane;
    float4 a0 = S[j0], a1 = S[j0+64], a2 = S[j0+128], a3 = S[j0+192];
    float v0 = fmaf(twoH, fmaf(pi.x,a0.x, fmaf(pi.y,a0.y, pi.z*a0.z)), a0.w + R);
    float v1 = fmaf(twoH, fmaf(pi.x,a1.x, fmaf(pi.y,a1.y, pi.z*a1.z)), a1.w + R);
    float v2 = fmaf(twoH, fmaf(pi.x,a2.x, fmaf(pi.y,a2.y, pi.z*a2.z)), a2.w + R);
    float v3 = fmaf(twoH, fmaf(pi.x,a3.x, fmaf(pi.y,a3.y, pi.z*a3.z)), a3.w + R);
    float m4 = fmaxf(fmaxf(v0, v1), fmaxf(v2, v3));
    float nm = fmaxf(mx, m4);
    s = fmaf(s, __expf(mx - nm),
             __expf(v0 - nm) + __expf(v1 - nm) + __expf(v2 - nm) + __expf(v3 - nm));
    mx = nm;
  }
  #pragma unroll
  for (int o = 32; o; o >>= 1){
    float om = __shfl_xor(mx, o, 64);
    float os = __shfl_xor(s,  o, 64);
    float nm = fmaxf(mx, om);
    s = fmaf(s, __expf(mx - nm), os*__expf(om - nm));
    mx = nm;
  }
  if (lane == 0) dOut[(size_t)b*NS + i] = oScale*(mx + __logf(s));
}

__global__ __launch_bounds__(1024) void sink_assign_kernel(const float4* __restrict__ tp,
                                                           const float4* __restrict__ yp,
                                                           float* __restrict__ lu,
                                                           float* __restrict__ lv,
                                                           int dir, float H, float twoH){
  __shared__ float4 S[NS];
  if (dir == 0) sink_pass_core(tp, 0,  yp, NS, lv, lu, H, twoH, 1.0f, 0.0f, -1.0f, S);
  else          sink_pass_core(yp, NS, tp, 0,  lu, lv, H, twoH, 1.0f, 0.0f, -1.0f, S);
}

// 3 OT problems fused along gridDim.y: p0=(x1,y) p1=(x1,x1) p2=(y,y)
__global__ __launch_bounds__(1024) void sink_ot_kernel(const float4* __restrict__ xp,
                                                       const float4* __restrict__ yp,
                                                       float* __restrict__ F,
                                                       float* __restrict__ G,
                                                       int dir, float H, float twoH,
                                                       float dMul, float dAdd, float oScale){
  __shared__ float4 S[NS];
  const int p = blockIdx.y;
  const float4* first  = (p == 2) ? yp : xp;
  const float4* second = (p == 1) ? xp : yp;
  float* f = F + (size_t)p*NB*NS;
  float* g = G + (size_t)p*NB*NS;
  if (dir == 0) sink_pass_core(first,  NS, second, NS, g, f, H, twoH, dMul, dAdd, oScale, S);
  else          sink_pass_core(second, NS, first,  NS, f, g, H, twoH, dMul, dAdd, oScale, S);
}

// target_perm[b,n,:] = sum_m exp(logK + lu_n + lv_m) * y_m
__global__ __launch_bounds__(1024) void perm_kernel(const float4* __restrict__ tp,
                                                    const float4* __restrict__ yp,
                                                    const float* __restrict__ lu,
                                                    const float* __restrict__ lv,
                                                    float* __restrict__ perm,
                                                    float H, float twoH){
  __shared__ float4 S[NS];
  const int tid = threadIdx.x, b = blockIdx.z;
  for (int j = tid; j < NS; j += 1024){
    float4 q = yp[(size_t)b*NS + j];
    float E = fmaf(-H, q.w, lv[(size_t)b*NS + j]);
    S[j] = make_float4(q.x, q.y, q.z, E);
  }
  __syncthreads();
  const int w = tid >> 6, lane = tid & 63;
  const int i = blockIdx.x*16 + w;
  const float4 pi = tp[i];
  const float R = fmaf(-H, pi.w, lu[(size_t)b*NS + i]);
  float a0 = 0.f, a1 = 0.f, a2 = 0.f;
  #pragma unroll 2
  for (int k = 0; k < 8; k++){
    #pragma unroll
    for (int u = 0; u < 4; u++){
      const int j = k*256 + u*64 + lane;
      float4 q = S[j];
      float val = fmaf(twoH, fmaf(pi.x,q.x, fmaf(pi.y,q.y, pi.z*q.z)), q.w + R);
      float wgt = __expf(val);
      a0 = fmaf(wgt, q.x, a0);
      a1 = fmaf(wgt, q.y, a1);
      a2 = fmaf(wgt, q.z, a2);
    }
  }
  #pragma unroll
  for (int o = 32; o; o >>= 1){
    a0 += __shfl_xor(a0, o, 64);
    a1 += __shfl_xor(a1, o, 64);
    a2 += __shfl_xor(a2, o, 64);
  }
  if (lane == 0){
    float* d = perm + ((size_t)b*NS + i)*3;
    d[0] = a0; d[1] = a1; d[2] = a2;
  }
}

// v_pred MLP (z-part prefolded into hb), loss_velocity partial, x1 pack
__global__ __launch_bounds__(128) void mlp_kernel(const float4* __restrict__ tp,
                                                  const float* __restrict__ perm,
                                                  const float* __restrict__ hb,
                                                  const float* __restrict__ W1,
                                                  const float* __restrict__ W2,
                                                  const float* __restrict__ b2,
                                                  const float* __restrict__ tarr,
                                                  float4* __restrict__ xp,
                                                  float* __restrict__ sumvel){
  __shared__ float sw0[256], sw1[256], sw2[256], shb[256], sW2[768];
  __shared__ float sred[2];
  const int tid = threadIdx.x;
  const int r = blockIdx.x*128 + tid;          // global row, batch-uniform per block
  const int b = r >> 11, n = r & (NS - 1);
  for (int k = tid; k < 256; k += 128){
    sw0[k] = W1[k]; sw1[k] = W1[256+k]; sw2[k] = W1[512+k]; shb[k] = hb[b*256 + k];
  }
  for (int k = tid; k < 768; k += 128) sW2[k] = W2[k];
  __syncthreads();
  const float t = fminf(fmaxf(tarr[b], 1e-5f), (float)(1.0 - 1e-5));
  const float4 T = tp[n];
  const float pm0 = perm[(size_t)r*3], pm1 = perm[(size_t)r*3+1], pm2 = perm[(size_t)r*3+2];
  const float omt = 1.0f - t;
  const float xt0 = omt*T.x + t*pm0;
  const float xt1 = omt*T.y + t*pm1;
  const float xt2 = omt*T.z + t*pm2;
  float a0 = b2[0], a1 = b2[1], a2 = b2[2];
  for (int cc = 0; cc < 256; cc++){
    float pre = fmaf(xt0, sw0[cc], fmaf(xt1, sw1[cc], fmaf(xt2, sw2[cc], shb[cc])));
    float h = fmaxf(pre, 0.0f);
    a0 = fmaf(h, sW2[3*cc],   a0);
    a1 = fmaf(h, sW2[3*cc+1], a1);
    a2 = fmaf(h, sW2[3*cc+2], a2);
  }
  const float vg0 = pm0 - T.x, vg1 = pm1 - T.y, vg2 = pm2 - T.z;
  const float d0 = a0 - vg0, d1 = a1 - vg1, d2 = a2 - vg2;
  float ls = fmaf(d0,d0, fmaf(d1,d1, d2*d2));
  const float x0 = T.x + a0, x1 = T.y + a1, x2 = T.z + a2;
  const float sq = fmaf(x0,x0, fmaf(x1,x1, x2*x2));
  xp[r] = make_float4(x0, x1, x2, sq);
  #pragma unroll
  for (int o = 32; o; o >>= 1) ls += __shfl_xor(ls, o, 64);
  if ((tid & 63) == 0) sred[tid >> 6] = ls;
  __syncthreads();
  if (tid == 0) atomicAdd(sumvel, sred[0] + sred[1]);
}

__global__ __launch_bounds__(256) void ot_sum_kernel(const float* __restrict__ F,
                                                     const float* __restrict__ G,
                                                     float* __restrict__ ot){
  __shared__ float sbuf[8];
  const int pb = blockIdx.x;                    // p*8 + b
  const float* f = F + (size_t)pb*NS;
  const float* g = G + (size_t)pb*NS;
  float sf = 0.f, sg = 0.f;
  for (int j = threadIdx.x; j < NS; j += 256){ sf += f[j]; sg += g[j]; }
  #pragma unroll
  for (int o = 32; o; o >>= 1){ sf += __shfl_xor(sf, o, 64); sg += __shfl_xor(sg, o, 64); }
  if ((threadIdx.x & 63) == 0){ sbuf[threadIdx.x >> 6] = sf; sbuf[4 + (threadIdx.x >> 6)] = sg; }
  __syncthreads();
  if (threadIdx.x == 0){
    float tf = 0.f, tg = 0.f;
    for (int w = 0; w < 4; w++){ tf += sbuf[w]; tg += sbuf[4 + w]; }
    ot[pb] = tf/(float)NS + tg/(float)NS;
  }
}

__global__ void finalize_kernel(const float* __restrict__ scal, float* __restrict__ out){
  if (threadIdx.x == 0){
    const float* ot = scal + 2;
    float lot = 0.f;
    for (int b = 0; b < NB; b++)
      lot += ot[0*NB + b] - 0.5f*ot[1*NB + b] - 0.5f*ot[2*NB + b];
    lot /= (float)NB;
    const float lvv = scal[0] / (float)(NB*NS*3);
    const float lrg = scal[1] / (float)NS;
    out[0] = lvv + 0.1f*lot + 0.01f*lrg;
    out[1] = lvv;
    out[2] = lot;
    out[3] = lrg;
  }
}

extern "C" void kernel_launch(void* const* d_in, const int* in_sizes, int n_in,
                              void* d_out, int out_size, void* d_ws, size_t ws_size,
                              hipStream_t stream){
  (void)in_sizes; (void)n_in; (void)out_size; (void)ws_size;
  const float* target = (const float*)d_in[0];
  const float* tarr   = (const float*)d_in[1];
  const float* tmpl   = (const float*)d_in[2];
  const float* Wenc   = (const float*)d_in[3];
  const float* benc   = (const float*)d_in[4];
  const float* W1     = (const float*)d_in[5];
  const float* b1     = (const float*)d_in[6];
  const float* W2     = (const float*)d_in[7];
  const float* b2     = (const float*)d_in[8];
  float* out = (float*)d_out;
  float* ws  = (float*)d_ws;

  float*  scal = ws + OFF_SCAL;
  float*  lu   = ws + OFF_LU;
  float*  lv   = ws + OFF_LV;
  float*  F    = ws + OFF_F;
  float*  G    = ws + OFF_G;
  int*    sel  = (int*)(ws + OFF_IDX);
  float4* yp   = (float4*)(ws + OFF_YP);
  float4* tp   = (float4*)(ws + OFF_TP);
  float4* xp   = (float4*)(ws + OFF_XP);
  float*  perm = ws + OFF_PERM;
  float*  z    = ws + OFF_Z;
  float*  hb   = ws + OFF_HB;

  hipMemsetAsync(ws, 0, (size_t)ZERO_FLOATS*sizeof(float), stream);

  fps_kernel<<<NB, 512, 0, stream>>>(target, sel);
  gather_pack_kernel<<<dim3(8, NB), 256, 0, stream>>>(target, sel, yp);
  pack_t_kernel<<<8, 256, 0, stream>>>(tmpl, tp, scal + 1);
  feat_z_kernel<<<NB, 256, 0, stream>>>(yp, Wenc, benc, z);
  hbase_kernel<<<NB, 256, 0, stream>>>(z, W1, b1, tarr, hb);

  const float INVREG = 1.0f/0.05f;
  for (int it = 0; it < 20; ++it){
    sink_assign_kernel<<<dim3(128,1,NB), 1024, 0, stream>>>(tp, yp, lu, lv, 0, INVREG, 2.0f*INVREG);
    sink_assign_kernel<<<dim3(128,1,NB), 1024, 0, stream>>>(tp, yp, lu, lv, 1, INVREG, 2.0f*INVREG);
  }
  perm_kernel<<<dim3(128,1,NB), 1024, 0, stream>>>(tp, yp, lu, lv, perm, INVREG, 2.0f*INVREG);
  mlp_kernel<<<128, 128, 0, stream>>>(tp, perm, hb, W1, W2, b2, tarr, xp, scal + 0);

  const float EPS    = (float)(0.05*0.05);
  const float INVEPS = 1.0f/EPS;
  const float HOT    = 0.5f*INVEPS;
  const float LOGNU  = (float)(-log(2048.0));
  for (int it = 0; it < 20; ++it){
    sink_ot_kernel<<<dim3(128,3,NB), 1024, 0, stream>>>(xp, yp, F, G, 0, HOT, INVEPS, INVEPS, LOGNU, -EPS);
    sink_ot_kernel<<<dim3(128,3,NB), 1024, 0, stream>>>(xp, yp, F, G, 1, HOT, INVEPS, INVEPS, LOGNU, -EPS);
  }
  ot_sum_kernel<<<24, 256, 0, stream>>>(F, G, scal + 2);
  finalize_kernel<<<1, 64, 0, stream>>>(scal, out);
}